// Round 12
// baseline (154.377 us; speedup 1.0000x reference)
//
#include <hip/hip_runtime.h>
#include <cmath>

#define WS 11
#define IMH 512
#define IMW 512
#define OH 502
#define OW 502
#define NPLANES 96                 // 32 * 3
#define STRIPW 48                  // output cols per wave strip
#define STRIPH 64                  // output rows per wave strip (4 subs x 16)
#define SUBH 16                    // rows per lane
#define XSTRIPS 11                 // ceil(502/48)
#define YSTRIPS 8                  // ceil(502/64)
#define NTASKS (XSTRIPS * YSTRIPS * NPLANES)   // 8448
#define WPB 4                      // waves per block (256 threads), 1 strip/wave
#define NBLK (NTASKS / WPB)        // 2112
#define NOUT ((long long)NPLANES * OH * OW)    // 24192384

typedef float f32x4 __attribute__((ext_vector_type(4)));

struct GaussW { float g[WS]; };

// DPP row_shl:N — lane i reads lane i+N within its 16-lane row (VALU, no LDS).
// Lanes whose (lane&15)+N > 15 keep their own value (old=src) — those feed
// only cmask-killed columns (g >= 12).
template<int N>
__device__ __forceinline__ float dpp_shl(float v) {
    int i = __float_as_int(v);
    int r = __builtin_amdgcn_update_dpp(i, i, 0x100 + N, 0xF, 0xF, false);
    return __int_as_float(r);
}

// ---------------- kernel 1: range-detection flags over img1 ----------------
__global__ __launch_bounds__(256) void flags_kernel(const float* __restrict__ img1,
                                                    unsigned* __restrict__ flags,
                                                    int n4) {
    int idx = blockIdx.x * blockDim.x + threadIdx.x;
    int stride = gridDim.x * blockDim.x;
    int gt = 0, lt = 0;
    const float4* p = reinterpret_cast<const float4*>(img1);
    for (int i = idx; i < n4; i += stride) {
        float4 v = p[i];
        gt |= (v.x > 128.f) | (v.y > 128.f) | (v.z > 128.f) | (v.w > 128.f);
        lt |= (v.x < -0.5f) | (v.y < -0.5f) | (v.z < -0.5f) | (v.w < -0.5f);
    }
    if (gt) atomicOr(&flags[0], 1u);
    if (lt) atomicOr(&flags[1], 1u);
}

// ---------------- kernel 2: LDS-free register-ring SSIM, 4-quantity form ----
// R11 body with one change: horizontal neighbor exchange via DPP row_shl
// (VALU, 0-latency) instead of __shfl/ds_bpermute (LDS pipe, lgkmcnt stalls).
// Lane layout g = lane&15 matches DPP 16-lane rows; g>=12 columns are masked.
__global__ __launch_bounds__(256) void ssim_kernel(const float* __restrict__ img1,
                                                   const float* __restrict__ img2,
                                                   const unsigned* __restrict__ flags,
                                                   double* __restrict__ sum_out,
                                                   double* __restrict__ partials,
                                                   int use_partials,
                                                   GaussW gw) {
    const int tid = threadIdx.x;
    const int wave = tid >> 6;
    const int lane = tid & 63;
    const int g = lane & 15;           // col group within strip
    const int s = lane >> 4;           // row sub within strip

    const int task = blockIdx.x * WPB + wave;
    const int plane = task / (XSTRIPS * YSTRIPS);
    const int rem = task - plane * (XSTRIPS * YSTRIPS);
    const int wy = rem / XSTRIPS;
    const int wx = rem - wy * XSTRIPS;

    const float* p1 = img1 + (size_t)plane * (IMH * IMW);
    const float* p2 = img2 + (size_t)plane * (IMH * IMW);

    const int x0 = wx * STRIPW;                     // strip's output col base
    int colbase = x0 + 4 * g;                       // this lane's input col base
    colbase = colbase <= IMW - 4 ? colbase : IMW - 4;  // clamp (masked outputs only)
    const int ys = wy * STRIPH + s * SUBH;          // first output row of this sub

    // constants from range flags
    float maxv = flags[0] ? 255.f : 1.f;
    float minv = flags[1] ? -1.f : 0.f;
    float L = maxv - minv;
    float C1 = (0.01f * L) * (0.01f * L);
    float C2 = (0.03f * L) * (0.03f * L);

    // ---- prime the 11-row ring (s,d) with rows ys .. ys+9 ----
    f32x4 rs[WS], rd[WS];
    #pragma unroll
    for (int k = 0; k < WS - 1; ++k) {
        int row = ys + k; row = row < IMH - 1 ? row : IMH - 1;
        const float* r1 = p1 + (size_t)row * IMW + colbase;
        const float* r2 = p2 + (size_t)row * IMW + colbase;
        f32x4 a = *reinterpret_cast<const f32x4*>(r1);
        f32x4 b = *reinterpret_cast<const f32x4*>(r2);
        rs[k] = a + b;
        rd[k] = a - b;
    }

    f32x4 acc4 = 0.f;    // per-column accumulators; masks applied after loop

    #pragma unroll
    for (int i = 0; i < SUBH; ++i) {
        // load row ys+i+10 into ring slot 10
        {
            int row = ys + i + (WS - 1); row = row < IMH - 1 ? row : IMH - 1;
            const float* r1 = p1 + (size_t)row * IMW + colbase;
            const float* r2 = p2 + (size_t)row * IMW + colbase;
            f32x4 a = *reinterpret_cast<const f32x4*>(r1);
            f32x4 b = *reinterpret_cast<const f32x4*>(r2);
            rs[WS - 1] = a + b;
            rd[WS - 1] = a - b;
        }

        // ---- vertical 11-tap conv of {s, d, s^2, d^2} (registers only) ----
        f32x4 S = 0.f, D = 0.f, P = 0.f, Q = 0.f;
        #pragma unroll
        for (int k = 0; k < WS; ++k) {
            float w = gw.g[k];
            f32x4 sv = rs[k], dv = rd[k];
            S += w * sv;
            D += w * dv;
            P += w * (sv * sv);
            Q += w * (dv * dv);
        }

        // ---- shift ring (SSA renames under full unroll) ----
        #pragma unroll
        for (int k = 0; k < WS - 1; ++k) { rs[k] = rs[k + 1]; rd[k] = rd[k + 1]; }

        // ---- horizontal 11-tap conv; neighbors via DPP row_shl (VALU) ----
        float hs[4][4];
        #pragma unroll
        for (int q = 0; q < 4; ++q) {
            f32x4 v = (q == 0) ? S : (q == 1) ? D : (q == 2) ? P : Q;
            float Wq[14];
            Wq[0] = v[0]; Wq[1] = v[1]; Wq[2] = v[2]; Wq[3] = v[3];
            Wq[4]  = dpp_shl<1>(v[0]);
            Wq[5]  = dpp_shl<1>(v[1]);
            Wq[6]  = dpp_shl<1>(v[2]);
            Wq[7]  = dpp_shl<1>(v[3]);
            Wq[8]  = dpp_shl<2>(v[0]);
            Wq[9]  = dpp_shl<2>(v[1]);
            Wq[10] = dpp_shl<2>(v[2]);
            Wq[11] = dpp_shl<2>(v[3]);
            Wq[12] = dpp_shl<3>(v[0]);
            Wq[13] = dpp_shl<3>(v[1]);
            #pragma unroll
            for (int c = 0; c < 4; ++c) {
                float acc = 0.f;
                #pragma unroll
                for (int k = 0; k < WS; ++k) acc += gw.g[k] * Wq[c + k];
                hs[q][c] = acc;
            }
        }

        // ---- SSIM map from 4-quantity form; row-masked accumulate ----
        const int oy = ys + i;
        float rowm = (oy < OH) ? 1.f : 0.f;
        #pragma unroll
        for (int c = 0; c < 4; ++c) {
            float hS = hs[0][c], hD = hs[1][c], Pv = hs[2][c], Qv = hs[3][c];
            float hS2 = hS * hS, hD2 = hD * hD;
            float mu12_2 = (hS2 - hD2) * 0.5f;   // 2*mu1*mu2
            float msq    = (hS2 + hD2) * 0.5f;   // mu1^2 + mu2^2
            float exy2   = (Pv - Qv) * 0.5f;     // 2*E[xy]
            float es     = (Pv + Qv) * 0.5f;     // E[x^2] + E[y^2]
            float v1 = (exy2 - mu12_2) + C2;     // 2*sigma12 + C2
            float v2 = (es - msq) + C2;          // sigma1+sigma2 + C2
            float num = (mu12_2 + C1) * v1;
            float den = (msq + C1) * v2;
            float rc = __builtin_amdgcn_rcpf(den);   // ~1 ulp, sufficient
            acc4[c] = fmaf(num * rc, rowm, acc4[c]);
        }
    }

    // ---- apply column masks once, then wave reduction ----
    float local = 0.f;
    #pragma unroll
    for (int c = 0; c < 4; ++c) {
        float cm = (g < 12 && (x0 + 4 * g + c) < OW) ? 1.f : 0.f;
        local = fmaf(acc4[c], cm, local);
    }

    #pragma unroll
    for (int off = 32; off > 0; off >>= 1)
        local += __shfl_down(local, off, 64);

    if (lane == 0) {
        if (use_partials) partials[task] = (double)local;
        else atomicAdd(sum_out, (double)local);
    }
}

// ---------------- kernel 3: final reduce + mean ----------------
__global__ __launch_bounds__(256) void reduce_kernel(const double* __restrict__ sum,
                                                     const double* __restrict__ partials,
                                                     int use_partials,
                                                     float* __restrict__ out) {
    if (use_partials) {
        double local = 0.0;
        for (int i = threadIdx.x; i < NTASKS; i += 256) local += partials[i];
        #pragma unroll
        for (int off = 32; off > 0; off >>= 1)
            local += __shfl_down(local, off, 64);
        __shared__ double ws2[4];
        int wave = threadIdx.x >> 6, lane = threadIdx.x & 63;
        if (lane == 0) ws2[wave] = local;
        __syncthreads();
        if (threadIdx.x == 0)
            out[0] = (float)((ws2[0] + ws2[1] + ws2[2] + ws2[3]) / (double)NOUT);
    } else {
        if (threadIdx.x == 0) out[0] = (float)(sum[0] / (double)NOUT);
    }
}

extern "C" void kernel_launch(void* const* d_in, const int* in_sizes, int n_in,
                              void* d_out, int out_size, void* d_ws, size_t ws_size,
                              hipStream_t stream) {
    const float* img1 = (const float*)d_in[0];
    const float* img2 = (const float*)d_in[1];
    float* out = (float*)d_out;

    // ws layout: [0..7] flags, [8..15] double sum, [16..] per-task partials
    unsigned* flags = (unsigned*)d_ws;
    double* sum = (double*)((char*)d_ws + 8);
    double* partials = (double*)((char*)d_ws + 16);
    int use_partials = (ws_size >= 16 + (size_t)NTASKS * sizeof(double)) ? 1 : 0;

    hipMemsetAsync(d_ws, 0, 16, stream);

    // Gaussian taps (float64 math then cast, matching numpy reference)
    GaussW gw;
    {
        double g[WS], ssum = 0.0;
        for (int i = 0; i < WS; ++i) {
            double x = (double)(i - WS / 2);
            g[i] = exp(-(x * x) / (2.0 * 1.5 * 1.5));
            ssum += g[i];
        }
        for (int i = 0; i < WS; ++i) gw.g[i] = (float)(g[i] / ssum);
    }

    int n = in_sizes[0];           // 25,165,824 floats
    flags_kernel<<<2048, 256, 0, stream>>>(img1, flags, n / 4);

    ssim_kernel<<<NBLK, 256, 0, stream>>>(img1, img2, flags, sum, partials, use_partials, gw);

    reduce_kernel<<<1, 256, 0, stream>>>(sum, partials, use_partials, out);
}

// Round 13
// 152.799 us; speedup vs baseline: 1.0103x; 1.0103x over previous
//
#include <hip/hip_runtime.h>
#include <cmath>

#define WS 11
#define IMH 512
#define IMW 512
#define OH 502
#define OW 502
#define NPLANES 96                 // 32 * 3
#define STRIPW 48                  // output cols per wave strip
#define SUBH 8                     // rows per lane
#define STRIPH (4 * SUBH)          // 32 output rows per wave strip
#define XSTRIPS 11                 // ceil(502/48)
#define YSTRIPS 16                 // ceil(502/32)
#define NTASKS (XSTRIPS * YSTRIPS * NPLANES)   // 16896
#define WPB 4                      // waves per block (256 threads), 1 strip/wave
#define NBLK (NTASKS / WPB)        // 4224
#define NOUT ((long long)NPLANES * OH * OW)    // 24192384

typedef float f32x4 __attribute__((ext_vector_type(4)));

struct GaussW { float g[WS]; };

// DPP row_shl:N — lane i reads lane i+N within its 16-lane row (VALU, no LDS).
// Lanes whose (lane&15)+N > 15 keep their own value (old=src) — those feed
// only cmask-killed columns (g >= 12).
template<int N>
__device__ __forceinline__ float dpp_shl(float v) {
    int i = __float_as_int(v);
    int r = __builtin_amdgcn_update_dpp(i, i, 0x100 + N, 0xF, 0xF, false);
    return __int_as_float(r);
}

// ---------------- kernel 1: range-detection flags over img1 ----------------
__global__ __launch_bounds__(256) void flags_kernel(const float* __restrict__ img1,
                                                    unsigned* __restrict__ flags,
                                                    int n4) {
    int idx = blockIdx.x * blockDim.x + threadIdx.x;
    int stride = gridDim.x * blockDim.x;
    int gt = 0, lt = 0;
    const float4* p = reinterpret_cast<const float4*>(img1);
    for (int i = idx; i < n4; i += stride) {
        float4 v = p[i];
        gt |= (v.x > 128.f) | (v.y > 128.f) | (v.z > 128.f) | (v.w > 128.f);
        lt |= (v.x < -0.5f) | (v.y < -0.5f) | (v.z < -0.5f) | (v.w < -0.5f);
    }
    if (gt) atomicOr(&flags[0], 1u);
    if (lt) atomicOr(&flags[1], 1u);
}

// ---------------- kernel 2: LDS-free register-ring SSIM, 4-quantity form ----
// R12 body, SUBH 16->8: strip = 48x32, 16896 wave-tasks (16.5 waves/SIMD of
// total work) so the machine can hold ~4 waves/SIMD (VGPR-capped) instead of
// averaging 1.5 — attacks the work-granularity residency cap identified in
// R12's post-mortem. Costs +38% VMEM instr (priming amortized over 8 rows
// not 16) — VMEM is at 17% of HBM peak, far from binding.
__global__ __launch_bounds__(256) void ssim_kernel(const float* __restrict__ img1,
                                                   const float* __restrict__ img2,
                                                   const unsigned* __restrict__ flags,
                                                   double* __restrict__ sum_out,
                                                   double* __restrict__ partials,
                                                   int use_partials,
                                                   GaussW gw) {
    const int tid = threadIdx.x;
    const int wave = tid >> 6;
    const int lane = tid & 63;
    const int g = lane & 15;           // col group within strip
    const int s = lane >> 4;           // row sub within strip

    const int task = blockIdx.x * WPB + wave;
    const int plane = task / (XSTRIPS * YSTRIPS);
    const int rem = task - plane * (XSTRIPS * YSTRIPS);
    const int wy = rem / XSTRIPS;
    const int wx = rem - wy * XSTRIPS;

    const float* p1 = img1 + (size_t)plane * (IMH * IMW);
    const float* p2 = img2 + (size_t)plane * (IMH * IMW);

    const int x0 = wx * STRIPW;                     // strip's output col base
    int colbase = x0 + 4 * g;                       // this lane's input col base
    colbase = colbase <= IMW - 4 ? colbase : IMW - 4;  // clamp (masked outputs only)
    const int ys = wy * STRIPH + s * SUBH;          // first output row of this sub

    // constants from range flags
    float maxv = flags[0] ? 255.f : 1.f;
    float minv = flags[1] ? -1.f : 0.f;
    float L = maxv - minv;
    float C1 = (0.01f * L) * (0.01f * L);
    float C2 = (0.03f * L) * (0.03f * L);

    // ---- prime the 11-row ring (s,d) with rows ys .. ys+9 ----
    f32x4 rs[WS], rd[WS];
    #pragma unroll
    for (int k = 0; k < WS - 1; ++k) {
        int row = ys + k; row = row < IMH - 1 ? row : IMH - 1;
        const float* r1 = p1 + (size_t)row * IMW + colbase;
        const float* r2 = p2 + (size_t)row * IMW + colbase;
        f32x4 a = *reinterpret_cast<const f32x4*>(r1);
        f32x4 b = *reinterpret_cast<const f32x4*>(r2);
        rs[k] = a + b;
        rd[k] = a - b;
    }

    f32x4 acc4 = 0.f;    // per-column accumulators; masks applied after loop

    #pragma unroll
    for (int i = 0; i < SUBH; ++i) {
        // load row ys+i+10 into ring slot 10
        {
            int row = ys + i + (WS - 1); row = row < IMH - 1 ? row : IMH - 1;
            const float* r1 = p1 + (size_t)row * IMW + colbase;
            const float* r2 = p2 + (size_t)row * IMW + colbase;
            f32x4 a = *reinterpret_cast<const f32x4*>(r1);
            f32x4 b = *reinterpret_cast<const f32x4*>(r2);
            rs[WS - 1] = a + b;
            rd[WS - 1] = a - b;
        }

        // ---- vertical 11-tap conv of {s, d, s^2, d^2} (registers only) ----
        f32x4 S = 0.f, D = 0.f, P = 0.f, Q = 0.f;
        #pragma unroll
        for (int k = 0; k < WS; ++k) {
            float w = gw.g[k];
            f32x4 sv = rs[k], dv = rd[k];
            S += w * sv;
            D += w * dv;
            P += w * (sv * sv);
            Q += w * (dv * dv);
        }

        // ---- shift ring (SSA renames under full unroll) ----
        #pragma unroll
        for (int k = 0; k < WS - 1; ++k) { rs[k] = rs[k + 1]; rd[k] = rd[k + 1]; }

        // ---- horizontal 11-tap conv; neighbors via DPP row_shl (VALU) ----
        float hs[4][4];
        #pragma unroll
        for (int q = 0; q < 4; ++q) {
            f32x4 v = (q == 0) ? S : (q == 1) ? D : (q == 2) ? P : Q;
            float Wq[14];
            Wq[0] = v[0]; Wq[1] = v[1]; Wq[2] = v[2]; Wq[3] = v[3];
            Wq[4]  = dpp_shl<1>(v[0]);
            Wq[5]  = dpp_shl<1>(v[1]);
            Wq[6]  = dpp_shl<1>(v[2]);
            Wq[7]  = dpp_shl<1>(v[3]);
            Wq[8]  = dpp_shl<2>(v[0]);
            Wq[9]  = dpp_shl<2>(v[1]);
            Wq[10] = dpp_shl<2>(v[2]);
            Wq[11] = dpp_shl<2>(v[3]);
            Wq[12] = dpp_shl<3>(v[0]);
            Wq[13] = dpp_shl<3>(v[1]);
            #pragma unroll
            for (int c = 0; c < 4; ++c) {
                float acc = 0.f;
                #pragma unroll
                for (int k = 0; k < WS; ++k) acc += gw.g[k] * Wq[c + k];
                hs[q][c] = acc;
            }
        }

        // ---- SSIM map from 4-quantity form; row-masked accumulate ----
        const int oy = ys + i;
        float rowm = (oy < OH) ? 1.f : 0.f;
        #pragma unroll
        for (int c = 0; c < 4; ++c) {
            float hS = hs[0][c], hD = hs[1][c], Pv = hs[2][c], Qv = hs[3][c];
            float hS2 = hS * hS, hD2 = hD * hD;
            float mu12_2 = (hS2 - hD2) * 0.5f;   // 2*mu1*mu2
            float msq    = (hS2 + hD2) * 0.5f;   // mu1^2 + mu2^2
            float exy2   = (Pv - Qv) * 0.5f;     // 2*E[xy]
            float es     = (Pv + Qv) * 0.5f;     // E[x^2] + E[y^2]
            float v1 = (exy2 - mu12_2) + C2;     // 2*sigma12 + C2
            float v2 = (es - msq) + C2;          // sigma1+sigma2 + C2
            float num = (mu12_2 + C1) * v1;
            float den = (msq + C1) * v2;
            float rc = __builtin_amdgcn_rcpf(den);   // ~1 ulp, sufficient
            acc4[c] = fmaf(num * rc, rowm, acc4[c]);
        }
    }

    // ---- apply column masks once, then wave reduction ----
    float local = 0.f;
    #pragma unroll
    for (int c = 0; c < 4; ++c) {
        float cm = (g < 12 && (x0 + 4 * g + c) < OW) ? 1.f : 0.f;
        local = fmaf(acc4[c], cm, local);
    }

    #pragma unroll
    for (int off = 32; off > 0; off >>= 1)
        local += __shfl_down(local, off, 64);

    if (lane == 0) {
        if (use_partials) partials[task] = (double)local;
        else atomicAdd(sum_out, (double)local);
    }
}

// ---------------- kernel 3: final reduce + mean ----------------
__global__ __launch_bounds__(256) void reduce_kernel(const double* __restrict__ sum,
                                                     const double* __restrict__ partials,
                                                     int use_partials,
                                                     float* __restrict__ out) {
    if (use_partials) {
        double local = 0.0;
        for (int i = threadIdx.x; i < NTASKS; i += 256) local += partials[i];
        #pragma unroll
        for (int off = 32; off > 0; off >>= 1)
            local += __shfl_down(local, off, 64);
        __shared__ double ws2[4];
        int wave = threadIdx.x >> 6, lane = threadIdx.x & 63;
        if (lane == 0) ws2[wave] = local;
        __syncthreads();
        if (threadIdx.x == 0)
            out[0] = (float)((ws2[0] + ws2[1] + ws2[2] + ws2[3]) / (double)NOUT);
    } else {
        if (threadIdx.x == 0) out[0] = (float)(sum[0] / (double)NOUT);
    }
}

extern "C" void kernel_launch(void* const* d_in, const int* in_sizes, int n_in,
                              void* d_out, int out_size, void* d_ws, size_t ws_size,
                              hipStream_t stream) {
    const float* img1 = (const float*)d_in[0];
    const float* img2 = (const float*)d_in[1];
    float* out = (float*)d_out;

    // ws layout: [0..7] flags, [8..15] double sum, [16..] per-task partials
    unsigned* flags = (unsigned*)d_ws;
    double* sum = (double*)((char*)d_ws + 8);
    double* partials = (double*)((char*)d_ws + 16);
    int use_partials = (ws_size >= 16 + (size_t)NTASKS * sizeof(double)) ? 1 : 0;

    hipMemsetAsync(d_ws, 0, 16, stream);

    // Gaussian taps (float64 math then cast, matching numpy reference)
    GaussW gw;
    {
        double g[WS], ssum = 0.0;
        for (int i = 0; i < WS; ++i) {
            double x = (double)(i - WS / 2);
            g[i] = exp(-(x * x) / (2.0 * 1.5 * 1.5));
            ssum += g[i];
        }
        for (int i = 0; i < WS; ++i) gw.g[i] = (float)(g[i] / ssum);
    }

    int n = in_sizes[0];           // 25,165,824 floats
    flags_kernel<<<2048, 256, 0, stream>>>(img1, flags, n / 4);

    ssim_kernel<<<NBLK, 256, 0, stream>>>(img1, img2, flags, sum, partials, use_partials, gw);

    reduce_kernel<<<1, 256, 0, stream>>>(sum, partials, use_partials, out);
}

// Round 14
// 150.936 us; speedup vs baseline: 1.0228x; 1.0123x over previous
//
#include <hip/hip_runtime.h>
#include <cmath>

#define WS 11
#define IMH 512
#define IMW 512
#define OH 502
#define OW 502
#define NPLANES 96                 // 32 * 3
#define STRIPW 48                  // output cols per wave strip
#define SUBH 8                     // rows per lane
#define STRIPH (4 * SUBH)          // 32 output rows per wave strip
#define XSTRIPS 11                 // ceil(502/48)
#define YSTRIPS 16                 // ceil(502/32)
#define NTASKS (XSTRIPS * YSTRIPS * NPLANES)   // 16896
#define WPB 4                      // waves per block (256 threads), 1 strip/wave
#define NBLK (NTASKS / WPB)        // 4224
#define NOUT ((long long)NPLANES * OH * OW)    // 24192384

typedef float f32x4 __attribute__((ext_vector_type(4)));

struct Taps {
    float g[WS];    // vertical taps
    float gs[WS];   // horizontal taps * (1/sqrt(2))  (for S, D)
    float gp[WS];   // horizontal taps * 0.5          (for P, Q)
};

// DPP row_shl:N — lane i reads lane i+N within its 16-lane row (VALU, no LDS).
// Lanes whose (lane&15)+N > 15 keep their own value (old=src) — those feed
// only cmask-killed columns (g >= 12).
template<int N>
__device__ __forceinline__ float dpp_shl(float v) {
    int i = __float_as_int(v);
    int r = __builtin_amdgcn_update_dpp(i, i, 0x100 + N, 0xF, 0xF, false);
    return __int_as_float(r);
}

// ---------------- kernel 1: range-detection flags over img1 ----------------
__global__ __launch_bounds__(256) void flags_kernel(const float* __restrict__ img1,
                                                    unsigned* __restrict__ flags,
                                                    int n4) {
    int idx = blockIdx.x * blockDim.x + threadIdx.x;
    int stride = gridDim.x * blockDim.x;
    int gt = 0, lt = 0;
    const float4* p = reinterpret_cast<const float4*>(img1);
    for (int i = idx; i < n4; i += stride) {
        float4 v = p[i];
        gt |= (v.x > 128.f) | (v.y > 128.f) | (v.z > 128.f) | (v.w > 128.f);
        lt |= (v.x < -0.5f) | (v.y < -0.5f) | (v.z < -0.5f) | (v.w < -0.5f);
    }
    if (gt) atomicOr(&flags[0], 1u);
    if (lt) atomicOr(&flags[1], 1u);
}

// ---------------- kernel 2: LDS-free register-ring SSIM, 4-quantity form ----
// R13 body + explicit 1-iteration load prefetch: iteration i computes its
// vertical conv purely from the 11-row ring while the row for iteration i+1
// is in flight in (na, nb) — removes the per-iteration exposed VMEM wait
// identified in R13's post-mortem (VALUBusy 84%, occupancy too low to hide
// latency via TLP). 0.5 factors folded into horizontal taps (gs, gp).
__global__ __launch_bounds__(256) void ssim_kernel(const float* __restrict__ img1,
                                                   const float* __restrict__ img2,
                                                   const unsigned* __restrict__ flags,
                                                   double* __restrict__ sum_out,
                                                   double* __restrict__ partials,
                                                   int use_partials,
                                                   Taps tp) {
    const int tid = threadIdx.x;
    const int wave = tid >> 6;
    const int lane = tid & 63;
    const int g = lane & 15;           // col group within strip
    const int s = lane >> 4;           // row sub within strip

    const int task = blockIdx.x * WPB + wave;
    const int plane = task / (XSTRIPS * YSTRIPS);
    const int rem = task - plane * (XSTRIPS * YSTRIPS);
    const int wy = rem / XSTRIPS;
    const int wx = rem - wy * XSTRIPS;

    const float* p1 = img1 + (size_t)plane * (IMH * IMW);
    const float* p2 = img2 + (size_t)plane * (IMH * IMW);

    const int x0 = wx * STRIPW;                     // strip's output col base
    int colbase = x0 + 4 * g;                       // this lane's input col base
    colbase = colbase <= IMW - 4 ? colbase : IMW - 4;  // clamp (masked outputs only)
    const int ys = wy * STRIPH + s * SUBH;          // first output row of this sub

    // constants from range flags
    float maxv = flags[0] ? 255.f : 1.f;
    float minv = flags[1] ? -1.f : 0.f;
    float L = maxv - minv;
    float C1 = (0.01f * L) * (0.01f * L);
    float C2 = (0.03f * L) * (0.03f * L);

    // ---- prime the FULL 11-row ring (s,d) with rows ys .. ys+10 ----
    f32x4 rs[WS], rd[WS];
    #pragma unroll
    for (int k = 0; k < WS; ++k) {
        int row = ys + k; row = row < IMH - 1 ? row : IMH - 1;
        const float* r1 = p1 + (size_t)row * IMW + colbase;
        const float* r2 = p2 + (size_t)row * IMW + colbase;
        f32x4 a = *reinterpret_cast<const f32x4*>(r1);
        f32x4 b = *reinterpret_cast<const f32x4*>(r2);
        rs[k] = a + b;
        rd[k] = a - b;
    }

    // ---- prefetch the row for iteration 1 ----
    f32x4 na, nb;
    {
        int row = ys + WS; row = row < IMH - 1 ? row : IMH - 1;
        na = *reinterpret_cast<const f32x4*>(p1 + (size_t)row * IMW + colbase);
        nb = *reinterpret_cast<const f32x4*>(p2 + (size_t)row * IMW + colbase);
    }

    f32x4 acc4 = 0.f;    // per-column accumulators; masks applied after loop

    #pragma unroll
    for (int i = 0; i < SUBH; ++i) {
        // ---- vertical 11-tap conv of {s, d, s^2, d^2} from the ring ----
        f32x4 S = 0.f, D = 0.f, P = 0.f, Q = 0.f;
        #pragma unroll
        for (int k = 0; k < WS; ++k) {
            float w = tp.g[k];
            f32x4 sv = rs[k], dv = rd[k];
            S += w * sv;
            D += w * dv;
            P += w * (sv * sv);
            Q += w * (dv * dv);
        }

        // ---- rotate ring, insert prefetched row, issue next prefetch ----
        #pragma unroll
        for (int k = 0; k < WS - 1; ++k) { rs[k] = rs[k + 1]; rd[k] = rd[k + 1]; }
        rs[WS - 1] = na + nb;
        rd[WS - 1] = na - nb;
        if (i < SUBH - 1) {
            int row = ys + i + WS + 1; row = row < IMH - 1 ? row : IMH - 1;
            na = *reinterpret_cast<const f32x4*>(p1 + (size_t)row * IMW + colbase);
            nb = *reinterpret_cast<const f32x4*>(p2 + (size_t)row * IMW + colbase);
        }

        // ---- horizontal 11-tap conv; neighbors via DPP row_shl (VALU) ----
        // taps pre-scaled: gs = g/sqrt2 (S,D), gp = g*0.5 (P,Q)
        float hs[4][4];
        #pragma unroll
        for (int q = 0; q < 4; ++q) {
            f32x4 v = (q == 0) ? S : (q == 1) ? D : (q == 2) ? P : Q;
            const float* tap = (q < 2) ? tp.gs : tp.gp;
            float Wq[14];
            Wq[0] = v[0]; Wq[1] = v[1]; Wq[2] = v[2]; Wq[3] = v[3];
            Wq[4]  = dpp_shl<1>(v[0]);
            Wq[5]  = dpp_shl<1>(v[1]);
            Wq[6]  = dpp_shl<1>(v[2]);
            Wq[7]  = dpp_shl<1>(v[3]);
            Wq[8]  = dpp_shl<2>(v[0]);
            Wq[9]  = dpp_shl<2>(v[1]);
            Wq[10] = dpp_shl<2>(v[2]);
            Wq[11] = dpp_shl<2>(v[3]);
            Wq[12] = dpp_shl<3>(v[0]);
            Wq[13] = dpp_shl<3>(v[1]);
            #pragma unroll
            for (int c = 0; c < 4; ++c) {
                float acc = 0.f;
                #pragma unroll
                for (int k = 0; k < WS; ++k) acc += tap[k] * Wq[c + k];
                hs[q][c] = acc;
            }
        }

        // ---- SSIM map (0.5 factors pre-folded into taps) ----
        const int oy = ys + i;
        float rowm = (oy < OH) ? 1.f : 0.f;
        #pragma unroll
        for (int c = 0; c < 4; ++c) {
            float hS = hs[0][c], hD = hs[1][c], Pv = hs[2][c], Qv = hs[3][c];
            float hS2 = hS * hS, hD2 = hD * hD;       // = mu-terms / 2 each
            float mu12_2 = hS2 - hD2;                 // 2*mu1*mu2
            float msq    = hS2 + hD2;                 // mu1^2 + mu2^2
            float exy2   = Pv - Qv;                   // 2*E[xy]
            float es     = Pv + Qv;                   // E[x^2] + E[y^2]
            float v1 = (exy2 - mu12_2) + C2;          // 2*sigma12 + C2
            float v2 = (es - msq) + C2;               // sigma1+sigma2 + C2
            float num = (mu12_2 + C1) * v1;
            float den = (msq + C1) * v2;
            float rc = __builtin_amdgcn_rcpf(den);    // ~1 ulp, sufficient
            acc4[c] = fmaf(num * rc, rowm, acc4[c]);
        }
    }

    // ---- apply column masks once, then wave reduction ----
    float local = 0.f;
    #pragma unroll
    for (int c = 0; c < 4; ++c) {
        float cm = (g < 12 && (x0 + 4 * g + c) < OW) ? 1.f : 0.f;
        local = fmaf(acc4[c], cm, local);
    }

    #pragma unroll
    for (int off = 32; off > 0; off >>= 1)
        local += __shfl_down(local, off, 64);

    if (lane == 0) {
        if (use_partials) partials[task] = (double)local;
        else atomicAdd(sum_out, (double)local);
    }
}

// ---------------- kernel 3: final reduce + mean ----------------
__global__ __launch_bounds__(256) void reduce_kernel(const double* __restrict__ sum,
                                                     const double* __restrict__ partials,
                                                     int use_partials,
                                                     float* __restrict__ out) {
    if (use_partials) {
        double local = 0.0;
        for (int i = threadIdx.x; i < NTASKS; i += 256) local += partials[i];
        #pragma unroll
        for (int off = 32; off > 0; off >>= 1)
            local += __shfl_down(local, off, 64);
        __shared__ double ws2[4];
        int wave = threadIdx.x >> 6, lane = threadIdx.x & 63;
        if (lane == 0) ws2[wave] = local;
        __syncthreads();
        if (threadIdx.x == 0)
            out[0] = (float)((ws2[0] + ws2[1] + ws2[2] + ws2[3]) / (double)NOUT);
    } else {
        if (threadIdx.x == 0) out[0] = (float)(sum[0] / (double)NOUT);
    }
}

extern "C" void kernel_launch(void* const* d_in, const int* in_sizes, int n_in,
                              void* d_out, int out_size, void* d_ws, size_t ws_size,
                              hipStream_t stream) {
    const float* img1 = (const float*)d_in[0];
    const float* img2 = (const float*)d_in[1];
    float* out = (float*)d_out;

    // ws layout: [0..7] flags, [8..15] double sum, [16..] per-task partials
    unsigned* flags = (unsigned*)d_ws;
    double* sum = (double*)((char*)d_ws + 8);
    double* partials = (double*)((char*)d_ws + 16);
    int use_partials = (ws_size >= 16 + (size_t)NTASKS * sizeof(double)) ? 1 : 0;

    hipMemsetAsync(d_ws, 0, 16, stream);

    // Gaussian taps (float64 math then cast, matching numpy reference)
    Taps tp;
    {
        double g[WS], ssum = 0.0;
        for (int i = 0; i < WS; ++i) {
            double x = (double)(i - WS / 2);
            g[i] = exp(-(x * x) / (2.0 * 1.5 * 1.5));
            ssum += g[i];
        }
        for (int i = 0; i < WS; ++i) {
            float gf = (float)(g[i] / ssum);
            tp.g[i]  = gf;
            tp.gs[i] = gf * 0.70710678118654752f;  // 1/sqrt(2)
            tp.gp[i] = gf * 0.5f;
        }
    }

    int n = in_sizes[0];           // 25,165,824 floats
    flags_kernel<<<2048, 256, 0, stream>>>(img1, flags, n / 4);

    ssim_kernel<<<NBLK, 256, 0, stream>>>(img1, img2, flags, sum, partials, use_partials, tp);

    reduce_kernel<<<1, 256, 0, stream>>>(sum, partials, use_partials, out);
}

// Round 15
// 139.523 us; speedup vs baseline: 1.1065x; 1.0818x over previous
//
#include <hip/hip_runtime.h>
#include <cmath>

#define WS 11
#define IMH 512
#define IMW 512
#define OH 502
#define OW 502
#define NPLANES 96                 // 32 * 3
#define STRIPW 52                  // output cols per wave strip (13 groups x 4)
#define SUBH 8                     // rows per lane
#define STRIPH (4 * SUBH)          // 32 output rows per wave strip
#define XSTRIPS 10                 // ceil(502/52)
#define YSTRIPS 16                 // ceil(502/32)
#define NTASKS (XSTRIPS * YSTRIPS * NPLANES)   // 15360
#define WPB 4                      // waves per block (256 threads), 1 strip/wave
#define NBLK (NTASKS / WPB)        // 3840
#define NOUT ((long long)NPLANES * OH * OW)    // 24192384

typedef float f32x4 __attribute__((ext_vector_type(4)));

struct Taps {
    float g[WS];    // vertical taps
    float gs[WS];   // horizontal taps * (1/sqrt(2))  (for S, D)
    float gp[WS];   // horizontal taps * 0.5          (for P, Q)
};

// DPP row_shl:N — lane i reads lane i+N within its 16-lane row (VALU, no LDS).
// Lanes whose (lane&15)+N > 15 keep their own value (old=src) — those feed
// only cmask-killed columns (g >= 13).
template<int N>
__device__ __forceinline__ float dpp_shl(float v) {
    int i = __float_as_int(v);
    int r = __builtin_amdgcn_update_dpp(i, i, 0x100 + N, 0xF, 0xF, false);
    return __int_as_float(r);
}

// ---------------- kernel 1: range-detection flags over img1 ----------------
__global__ __launch_bounds__(256) void flags_kernel(const float* __restrict__ img1,
                                                    unsigned* __restrict__ flags,
                                                    int n4) {
    int idx = blockIdx.x * blockDim.x + threadIdx.x;
    int stride = gridDim.x * blockDim.x;
    int gt = 0, lt = 0;
    const float4* p = reinterpret_cast<const float4*>(img1);
    for (int i = idx; i < n4; i += stride) {
        float4 v = p[i];
        gt |= (v.x > 128.f) | (v.y > 128.f) | (v.z > 128.f) | (v.w > 128.f);
        lt |= (v.x < -0.5f) | (v.y < -0.5f) | (v.z < -0.5f) | (v.w < -0.5f);
    }
    if (gt) atomicOr(&flags[0], 1u);
    if (lt) atomicOr(&flags[1], 1u);
}

// ---------------- kernel 2: LDS-free register-ring SSIM, 4-quantity form ----
// R14 body with two instruction-count cuts:
//  (1) STRIPW 52 / mask g<13 — dpp_shl<3> is valid through g=12 (lane 15
//      exists), so only 3/16 lane-columns are wasted instead of 4/16;
//      tasks drop 16896 -> 15360 (-9%).
//  (2) symmetric-tap pairing for the squared quantities in the vertical
//      conv: P += w*(s[k]^2 + s[10-k]^2) = mul+fma+fma per pair (3 ops)
//      vs 4 unpaired — saves 40 VALU/iter (~7%).
__global__ __launch_bounds__(256) void ssim_kernel(const float* __restrict__ img1,
                                                   const float* __restrict__ img2,
                                                   const unsigned* __restrict__ flags,
                                                   double* __restrict__ sum_out,
                                                   double* __restrict__ partials,
                                                   int use_partials,
                                                   Taps tp) {
    const int tid = threadIdx.x;
    const int wave = tid >> 6;
    const int lane = tid & 63;
    const int g = lane & 15;           // col group within strip
    const int s = lane >> 4;           // row sub within strip

    const int task = blockIdx.x * WPB + wave;
    const int plane = task / (XSTRIPS * YSTRIPS);
    const int rem = task - plane * (XSTRIPS * YSTRIPS);
    const int wy = rem / XSTRIPS;
    const int wx = rem - wy * XSTRIPS;

    const float* p1 = img1 + (size_t)plane * (IMH * IMW);
    const float* p2 = img2 + (size_t)plane * (IMH * IMW);

    const int x0 = wx * STRIPW;                     // strip's output col base
    int colbase = x0 + 4 * g;                       // this lane's input col base
    colbase = colbase <= IMW - 4 ? colbase : IMW - 4;  // clamp (masked outputs only)
    const int ys = wy * STRIPH + s * SUBH;          // first output row of this sub

    // constants from range flags
    float maxv = flags[0] ? 255.f : 1.f;
    float minv = flags[1] ? -1.f : 0.f;
    float L = maxv - minv;
    float C1 = (0.01f * L) * (0.01f * L);
    float C2 = (0.03f * L) * (0.03f * L);

    // ---- prime the FULL 11-row ring (s,d) with rows ys .. ys+10 ----
    f32x4 rs[WS], rd[WS];
    #pragma unroll
    for (int k = 0; k < WS; ++k) {
        int row = ys + k; row = row < IMH - 1 ? row : IMH - 1;
        const float* r1 = p1 + (size_t)row * IMW + colbase;
        const float* r2 = p2 + (size_t)row * IMW + colbase;
        f32x4 a = *reinterpret_cast<const f32x4*>(r1);
        f32x4 b = *reinterpret_cast<const f32x4*>(r2);
        rs[k] = a + b;
        rd[k] = a - b;
    }

    // ---- prefetch the row for iteration 1 ----
    f32x4 na, nb;
    {
        int row = ys + WS; row = row < IMH - 1 ? row : IMH - 1;
        na = *reinterpret_cast<const f32x4*>(p1 + (size_t)row * IMW + colbase);
        nb = *reinterpret_cast<const f32x4*>(p2 + (size_t)row * IMW + colbase);
    }

    f32x4 acc4 = 0.f;    // per-column accumulators; masks applied after loop

    #pragma unroll
    for (int i = 0; i < SUBH; ++i) {
        // ---- vertical 11-tap conv of {s, d, s^2, d^2} from the ring ----
        // symmetric taps: pair k with 10-k (g[k] == g[10-k])
        f32x4 S, D, P, Q;
        {
            float w = tp.g[5];
            f32x4 sc = rs[5], dc = rd[5];
            S = w * sc;
            D = w * dc;
            P = w * (sc * sc);
            Q = w * (dc * dc);
        }
        #pragma unroll
        for (int k = 0; k < 5; ++k) {
            float w = tp.g[k];
            f32x4 sa = rs[k], sb = rs[10 - k];
            f32x4 da = rd[k], db = rd[10 - k];
            S += w * (sa + sb);
            D += w * (da + db);
            P += w * (sa * sa + sb * sb);   // mul, fma, fma
            Q += w * (da * da + db * db);
        }

        // ---- rotate ring, insert prefetched row, issue next prefetch ----
        #pragma unroll
        for (int k = 0; k < WS - 1; ++k) { rs[k] = rs[k + 1]; rd[k] = rd[k + 1]; }
        rs[WS - 1] = na + nb;
        rd[WS - 1] = na - nb;
        if (i < SUBH - 1) {
            int row = ys + i + WS + 1; row = row < IMH - 1 ? row : IMH - 1;
            na = *reinterpret_cast<const f32x4*>(p1 + (size_t)row * IMW + colbase);
            nb = *reinterpret_cast<const f32x4*>(p2 + (size_t)row * IMW + colbase);
        }

        // ---- horizontal 11-tap conv; neighbors via DPP row_shl (VALU) ----
        // taps pre-scaled: gs = g/sqrt2 (S,D), gp = g*0.5 (P,Q)
        float hs[4][4];
        #pragma unroll
        for (int q = 0; q < 4; ++q) {
            f32x4 v = (q == 0) ? S : (q == 1) ? D : (q == 2) ? P : Q;
            const float* tap = (q < 2) ? tp.gs : tp.gp;
            float Wq[14];
            Wq[0] = v[0]; Wq[1] = v[1]; Wq[2] = v[2]; Wq[3] = v[3];
            Wq[4]  = dpp_shl<1>(v[0]);
            Wq[5]  = dpp_shl<1>(v[1]);
            Wq[6]  = dpp_shl<1>(v[2]);
            Wq[7]  = dpp_shl<1>(v[3]);
            Wq[8]  = dpp_shl<2>(v[0]);
            Wq[9]  = dpp_shl<2>(v[1]);
            Wq[10] = dpp_shl<2>(v[2]);
            Wq[11] = dpp_shl<2>(v[3]);
            Wq[12] = dpp_shl<3>(v[0]);
            Wq[13] = dpp_shl<3>(v[1]);
            #pragma unroll
            for (int c = 0; c < 4; ++c) {
                float acc = 0.f;
                #pragma unroll
                for (int k = 0; k < WS; ++k) acc += tap[k] * Wq[c + k];
                hs[q][c] = acc;
            }
        }

        // ---- SSIM map (0.5 factors pre-folded into taps) ----
        const int oy = ys + i;
        float rowm = (oy < OH) ? 1.f : 0.f;
        #pragma unroll
        for (int c = 0; c < 4; ++c) {
            float hS = hs[0][c], hD = hs[1][c], Pv = hs[2][c], Qv = hs[3][c];
            float hS2 = hS * hS, hD2 = hD * hD;       // = mu-terms / 2 each
            float mu12_2 = hS2 - hD2;                 // 2*mu1*mu2
            float msq    = hS2 + hD2;                 // mu1^2 + mu2^2
            float exy2   = Pv - Qv;                   // 2*E[xy]
            float es     = Pv + Qv;                   // E[x^2] + E[y^2]
            float v1 = (exy2 - mu12_2) + C2;          // 2*sigma12 + C2
            float v2 = (es - msq) + C2;               // sigma1+sigma2 + C2
            float num = (mu12_2 + C1) * v1;
            float den = (msq + C1) * v2;
            float rc = __builtin_amdgcn_rcpf(den);    // ~1 ulp, sufficient
            acc4[c] = fmaf(num * rc, rowm, acc4[c]);
        }
    }

    // ---- apply column masks once, then wave reduction ----
    float local = 0.f;
    #pragma unroll
    for (int c = 0; c < 4; ++c) {
        float cm = (g < 13 && (x0 + 4 * g + c) < OW) ? 1.f : 0.f;
        local = fmaf(acc4[c], cm, local);
    }

    #pragma unroll
    for (int off = 32; off > 0; off >>= 1)
        local += __shfl_down(local, off, 64);

    if (lane == 0) {
        if (use_partials) partials[task] = (double)local;
        else atomicAdd(sum_out, (double)local);
    }
}

// ---------------- kernel 3: final reduce + mean ----------------
__global__ __launch_bounds__(256) void reduce_kernel(const double* __restrict__ sum,
                                                     const double* __restrict__ partials,
                                                     int use_partials,
                                                     float* __restrict__ out) {
    if (use_partials) {
        double local = 0.0;
        for (int i = threadIdx.x; i < NTASKS; i += 256) local += partials[i];
        #pragma unroll
        for (int off = 32; off > 0; off >>= 1)
            local += __shfl_down(local, off, 64);
        __shared__ double ws2[4];
        int wave = threadIdx.x >> 6, lane = threadIdx.x & 63;
        if (lane == 0) ws2[wave] = local;
        __syncthreads();
        if (threadIdx.x == 0)
            out[0] = (float)((ws2[0] + ws2[1] + ws2[2] + ws2[3]) / (double)NOUT);
    } else {
        if (threadIdx.x == 0) out[0] = (float)(sum[0] / (double)NOUT);
    }
}

extern "C" void kernel_launch(void* const* d_in, const int* in_sizes, int n_in,
                              void* d_out, int out_size, void* d_ws, size_t ws_size,
                              hipStream_t stream) {
    const float* img1 = (const float*)d_in[0];
    const float* img2 = (const float*)d_in[1];
    float* out = (float*)d_out;

    // ws layout: [0..7] flags, [8..15] double sum, [16..] per-task partials
    unsigned* flags = (unsigned*)d_ws;
    double* sum = (double*)((char*)d_ws + 8);
    double* partials = (double*)((char*)d_ws + 16);
    int use_partials = (ws_size >= 16 + (size_t)NTASKS * sizeof(double)) ? 1 : 0;

    hipMemsetAsync(d_ws, 0, 16, stream);

    // Gaussian taps (float64 math then cast, matching numpy reference)
    Taps tp;
    {
        double g[WS], ssum = 0.0;
        for (int i = 0; i < WS; ++i) {
            double x = (double)(i - WS / 2);
            g[i] = exp(-(x * x) / (2.0 * 1.5 * 1.5));
            ssum += g[i];
        }
        for (int i = 0; i < WS; ++i) {
            float gf = (float)(g[i] / ssum);
            tp.g[i]  = gf;
            tp.gs[i] = gf * 0.70710678118654752f;  // 1/sqrt(2)
            tp.gp[i] = gf * 0.5f;
        }
    }

    int n = in_sizes[0];           // 25,165,824 floats
    flags_kernel<<<2048, 256, 0, stream>>>(img1, flags, n / 4);

    ssim_kernel<<<NBLK, 256, 0, stream>>>(img1, img2, flags, sum, partials, use_partials, tp);

    reduce_kernel<<<1, 256, 0, stream>>>(sum, partials, use_partials, out);
}